// Round 5
// baseline (258.138 us; speedup 1.0000x reference)
//
#include <hip/hip_runtime.h>

// DeformableConv1d: B=32, C=64, L=16384, COUT=64, K=1.
// R6: multi-tile pipelined blocks (R5 was a serial 5-phase latency chain;
// nothing >43% busy). Each block runs NT=4 consecutive l-tiles with
// double-buffered XtH and T14 async-STAGE split:
//   interval1: issue next-tile global loads -> mm1+gather+XdWrite(cur)
//              -> halo LDS->LDS copy + staged-reg LDS write (next) -> bar
//   interval2: mm2(Xd) + store -> bar
// Halo rows 0..7 of tile t+1 == rows 64..71 of tile t -> LDS copy, no
// global re-read. Weights converted once per block. Grid 2048 blocks.
// LDS 29952 B -> 5 blocks/CU. Layouts identical to R5 (verified):
//   XtH: f16 [row][c], 72 rows, stride 36 words, XOR-swizzled b128 blocks
//   Xd : f16 [l][c],  64 rows, same stride/swizzle
// frac computed from p = l + offset in fp32, matching reference exactly.

#define BDIM 256
#define BB   32
#define CC   64
#define LL   16384
#define TL   64                  // l per tile
#define HH   4                   // gather halo (offset std 0.577 -> 6.9 sigma)
#define ROWS (TL + 2*HH)         // 72 staged rows
#define RSW  36                  // row stride (words, 144 B)
#define RSH  72                  // row stride (halfwords)
#define NT   4                   // tiles per block
#define XTB  10368               // one XtH buffer, bytes

typedef __fp16 half_t;
typedef __attribute__((ext_vector_type(2))) __fp16 h2;
typedef __attribute__((ext_vector_type(8))) __fp16 h8;
typedef __attribute__((ext_vector_type(4))) float f4;

union H2U { h2 h; unsigned u; };
union H8U { unsigned u[4]; h8 v; };

static __device__ __forceinline__ unsigned pk(float a, float b) {
    H2U r; r.h = __builtin_amdgcn_cvt_pkrtz(a, b); return r.u;
}

// split A-frag (weights) from global fp32: lane holds W[row][k0..k0+7]
static __device__ __forceinline__ void load_a_split(const float* __restrict__ wp,
                                                    int row, int ks, int q,
                                                    h8* ahi, h8* alo) {
    const float* base = wp + row * 64 + ks * 32 + q * 8;
    float4 w0 = *(const float4*)base;
    float4 w1 = *(const float4*)(base + 4);
    float v[8] = {w0.x, w0.y, w0.z, w0.w, w1.x, w1.y, w1.z, w1.w};
    H8U h, l;
    #pragma unroll
    for (int p = 0; p < 4; ++p) {
        H2U hh; hh.h = __builtin_amdgcn_cvt_pkrtz(v[2*p], v[2*p+1]);
        h.u[p] = hh.u;
        l.u[p] = pk(v[2*p] - (float)hh.h[0], v[2*p+1] - (float)hh.h[1]);
    }
    *ahi = h.v; *alo = l.v;
}

static __device__ __forceinline__ h8 load_a_f16(const float* __restrict__ wp,
                                                int row, int ks, int q) {
    const float* base = wp + row * 64 + ks * 32 + q * 8;
    float4 w0 = *(const float4*)base;
    float4 w1 = *(const float4*)(base + 4);
    float v[8] = {w0.x, w0.y, w0.z, w0.w, w1.x, w1.y, w1.z, w1.w};
    H8U r;
    #pragma unroll
    for (int p = 0; p < 4; ++p) r.u[p] = pk(v[2*p], v[2*p+1]);
    return r.v;
}

// write one 4ch x 4l staged tile (channels c0..c0+3, rows rowb..rowb+3)
static __device__ __forceinline__ void stage_write4(unsigned* dst, int cb, int rowb,
                                                    const float4& v0, const float4& v1,
                                                    const float4& v2, const float4& v3) {
    float a0[4] = {v0.x, v0.y, v0.z, v0.w};
    float a1[4] = {v1.x, v1.y, v1.z, v1.w};
    float a2[4] = {v2.x, v2.y, v2.z, v2.w};
    float a3[4] = {v3.x, v3.y, v3.z, v3.w};
    int wbase = rowb * RSW + (((cb >> 1) ^ ((rowb >> 2) & 7)) << 2) + 2 * (cb & 1);
    #pragma unroll
    for (int rl = 0; rl < 4; ++rl) {
        uint2 hw;
        hw.x = pk(a0[rl], a1[rl]);
        hw.y = pk(a2[rl], a3[rl]);
        *(uint2*)&dst[wbase + rl * RSW] = hw;
    }
}

__global__ __launch_bounds__(BDIM)
void deform_conv1d_r6(const float* __restrict__ x,
                      const float* __restrict__ offw,
                      const float* __restrict__ offb,
                      const float* __restrict__ regw,
                      const float* __restrict__ regb,
                      float* __restrict__ out) {
    __shared__ __align__(16) unsigned char smem[2 * XTB + 9216];
    unsigned* XdW = (unsigned*)(smem + 2 * XTB);

    const int tid = threadIdx.x;
    const int bx  = blockIdx.x;           // 0..63
    const int b   = blockIdx.y;
    const size_t xb = (size_t)b * CC * LL;

    const int wv   = tid >> 6;
    const int lane = tid & 63;
    const int q    = lane >> 4;
    const int n    = lane & 15;
    const int scb  = tid >> 4;            // stage channel-block 0..15
    const int slb  = tid & 15;            // stage l-block 0..15 (fast: coalesce)

    // ---------------- prologue: stage tile NT*bx into buffer 0 --------------
    {
        const int lg0 = (NT * bx) * TL;
        unsigned* dst = (unsigned*)smem;
        half_t*  dsth = (half_t*)smem;
        if (bx == 0) {                                // clamped slow path
            for (int i = tid; i < ROWS * CC; i += BDIM) {
                int r = i >> 6, c = i & 63;
                int g = min(max(lg0 - HH + r, 0), LL - 1);
                float v = x[xb + (size_t)c * LL + g];
                int blk = (c >> 3) ^ ((r >> 2) & 7);
                dsth[r * RSH + (blk << 3) + (c & 7)] = (half_t)v;
            }
        } else {
            // rows 8..71: one 4x4 tile per thread  (l = lg0-4+row)
            const float* pp = x + xb + (size_t)(4 * scb) * LL + (lg0 + 4 + 4 * slb);
            float4 v0 = *(const float4*)pp;
            float4 v1 = *(const float4*)(pp + LL);
            float4 v2 = *(const float4*)(pp + 2 * LL);
            float4 v3 = *(const float4*)(pp + 3 * LL);
            stage_write4(dst, scb, 8 + 4 * slb, v0, v1, v2, v3);
            // rows 0..7: threads 0..31
            if (tid < 32) {
                int lb2 = tid & 1, cb2 = tid >> 1;
                const float* p2 = x + xb + (size_t)(4 * cb2) * LL + (lg0 - 4 + 4 * lb2);
                float4 u0 = *(const float4*)p2;
                float4 u1 = *(const float4*)(p2 + LL);
                float4 u2 = *(const float4*)(p2 + 2 * LL);
                float4 u3 = *(const float4*)(p2 + 3 * LL);
                stage_write4(dst, cb2, 4 * lb2, u0, u1, u2, u3);
            }
        }
    }

    // ---------------- weights/biases: once per block ------------------------
    h8 ahi[2], alo[2], a2f[2];
    load_a_split(offw, 16 * wv + n, 0, q, &ahi[0], &alo[0]);
    load_a_split(offw, 16 * wv + n, 1, q, &ahi[1], &alo[1]);
    a2f[0] = load_a_f16(regw, 16 * wv + n, 0, q);
    a2f[1] = load_a_f16(regw, 16 * wv + n, 1, q);
    float4 bo = *(const float4*)(offb + 16 * wv + 4 * q);
    float4 br = *(const float4*)(regb + 16 * wv + 4 * q);
    __syncthreads();

    #pragma unroll
    for (int tt = 0; tt < NT; ++tt) {
        const int lg0 = (NT * bx + tt) * TL;
        unsigned* Xc  = (unsigned*)(smem + (tt & 1) * XTB);
        unsigned* Xn  = (unsigned*)(smem + ((tt & 1) ^ 1) * XTB);
        half_t*   Xch = (half_t*)Xc;
        const bool has_next  = (tt < NT - 1);
        const bool next_fast = has_next && !(bx == 63 && tt == NT - 2);

        // ---- issue next-tile main loads (rows 8..71, l = lg0+64-4+row) ----
        float4 s0, s1, s2, s3;
        if (next_fast) {
            const float* pp = x + xb + (size_t)(4 * scb) * LL + (lg0 + TL + 4 + 4 * slb);
            s0 = *(const float4*)pp;
            s1 = *(const float4*)(pp + LL);
            s2 = *(const float4*)(pp + 2 * LL);
            s3 = *(const float4*)(pp + 3 * LL);
        }

        // ---- matmul 1: offsets = Wo*x + bo (2-pass split weight) ----------
        f4 acc[4];
        #pragma unroll
        for (int nt = 0; nt < 4; ++nt) acc[nt] = (f4){bo.x, bo.y, bo.z, bo.w};
        #pragma unroll
        for (int nt = 0; nt < 4; ++nt) {
            const int r  = 16 * nt + n + HH;
            const int rb = r * RSW;
            const int sb = (r >> 2) & 7;
            #pragma unroll
            for (int ks = 0; ks < 2; ++ks) {
                int blk = (4 * ks + q) ^ sb;
                h8 bv = *(const h8*)&Xc[rb + (blk << 2)];
                acc[nt] = __builtin_amdgcn_mfma_f32_16x16x32_f16(ahi[ks], bv, acc[nt], 0, 0, 0);
                acc[nt] = __builtin_amdgcn_mfma_f32_16x16x32_f16(alo[ks], bv, acc[nt], 0, 0, 0);
            }
        }

        // ---- gather + lerp (acc := x_deform), ref-exact frac --------------
        #pragma unroll
        for (int nt = 0; nt < 4; ++nt) {
            const int l = lg0 + 16 * nt + n;
            #pragma unroll
            for (int reg = 0; reg < 4; ++reg) {
                const int c = 16 * wv + 4 * q + reg;
                float o  = acc[nt][reg];
                float p  = (float)l + o;
                p = __builtin_amdgcn_fmed3f(p, 0.0f, (float)(LL - 1));
                float of = floorf(p);
                float fr = p - of;
                int idx  = (int)of;
                int u    = idx - lg0 + HH;
                float x0, x1;
                if ((unsigned)u <= (unsigned)(ROWS - 2)) {
                    int b0 = (c >> 3) ^ ((u >> 2) & 7);
                    int b1 = (c >> 3) ^ (((u + 1) >> 2) & 7);
                    x0 = (float)Xch[u * RSH + (b0 << 3) + (c & 7)];
                    x1 = (float)Xch[(u + 1) * RSH + (b1 << 3) + (c & 7)];
                } else {                               // |off|>4: ~never
                    const float* xr = x + xb + (size_t)c * LL;
                    x0 = xr[idx];
                    x1 = xr[idx + (fr > 0.0f ? 1 : 0)];
                }
                acc[nt][reg] = x0 + fr * (x1 - x0);
            }
        }

        // ---- x_deform -> Xd[l][c] f16, block-XOR swizzled ------------------
        #pragma unroll
        for (int nt = 0; nt < 4; ++nt) {
            const int row = 16 * nt + n;
            const int sb  = (row >> 2) & 7;
            const int bw  = (2 * wv + (q >> 1)) ^ sb;
            uint2 pw;
            pw.x = pk(acc[nt][0], acc[nt][1]);
            pw.y = pk(acc[nt][2], acc[nt][3]);
            *(uint2*)&XdW[row * RSW + (bw << 2) + 2 * (q & 1)] = pw;
        }

        // ---- halo copy + staged write into next buffer ---------------------
        if (has_next) {
            // rows 0..7 of next tile == rows 64..71 of current (same swizzle)
            if (tid < 144) {
                int j  = tid / 18;
                int k2 = (tid - 18 * j) * 2;
                *(uint2*)&Xn[j * RSW + k2] = *(const uint2*)&Xc[(64 + j) * RSW + k2];
            }
            if (next_fast) {
                stage_write4(Xn, scb, 8 + 4 * slb, s0, s1, s2, s3);
            } else {                                   // tile 255: clamped
                half_t* Xnh = (half_t*)Xn;
                for (int i = tid; i < TL * CC; i += BDIM) {
                    int r = 8 + (i >> 6), c = i & 63;
                    int g = min(lg0 + TL - HH + r, LL - 1);
                    float v = x[xb + (size_t)c * LL + g];
                    int blk = (c >> 3) ^ ((r >> 2) & 7);
                    Xnh[r * RSH + (blk << 3) + (c & 7)] = (half_t)v;
                }
            }
        }
        __syncthreads();

        // ---- matmul 2: out = Wr * x_deform + br ---------------------------
        #pragma unroll
        for (int nt = 0; nt < 4; ++nt) acc[nt] = (f4){br.x, br.y, br.z, br.w};
        #pragma unroll
        for (int nt = 0; nt < 4; ++nt) {
            const int row = 16 * nt + n;
            const int sb  = (row >> 2) & 7;
            #pragma unroll
            for (int ks = 0; ks < 2; ++ks) {
                int blk = (4 * ks + q) ^ sb;
                h8 bv = *(const h8*)&XdW[row * RSW + (blk << 2)];
                acc[nt] = __builtin_amdgcn_mfma_f32_16x16x32_f16(a2f[ks], bv, acc[nt], 0, 0, 0);
            }
        }

        // ---- store ---------------------------------------------------------
        float* op = out + (size_t)b * CC * LL;
        #pragma unroll
        for (int nt = 0; nt < 4; ++nt) {
            #pragma unroll
            for (int reg = 0; reg < 4; ++reg) {
                op[(size_t)(16 * wv + 4 * q + reg) * LL + lg0 + 16 * nt + n] = acc[nt][reg];
            }
        }
        if (tt < NT - 1) __syncthreads();   // Xd free for next tile's writes
    }
}

extern "C" void kernel_launch(void* const* d_in, const int* in_sizes, int n_in,
                              void* d_out, int out_size, void* d_ws, size_t ws_size,
                              hipStream_t stream) {
    const float* x    = (const float*)d_in[0];   // [32,64,16384]
    const float* offw = (const float*)d_in[1];   // [64,64,1]
    const float* offb = (const float*)d_in[2];   // [64]
    const float* regw = (const float*)d_in[3];   // [64,64,1]
    const float* regb = (const float*)d_in[4];   // [64]
    float* out = (float*)d_out;                  // [32,64,16384]

    dim3 grid(LL / TL / NT, BB);
    deform_conv1d_r6<<<grid, dim3(BDIM), 0, stream>>>(x, offw, offb, regw, regb, out);
}